// Round 17
// baseline (234.082 us; speedup 1.0000x reference)
//
#include <hip/hip_runtime.h>
#include <math.h>

typedef __attribute__((ext_vector_type(4))) float f32x4;
typedef __attribute__((ext_vector_type(8))) short bf16x8;

constexpr int BATCH = 256;
constexpr int TT    = 64;
constexpr int NH    = 4;
constexpr int DH    = 64;
constexpr int HIDN  = 256;
constexpr int INDIM = 170;
constexpr int KPAD  = 192;
constexpr int ROWS  = BATCH * TT;    // 16384
constexpr float EPS = 1e-5f;

#define MF(a, b, c) __builtin_amdgcn_mfma_f32_16x16x32_bf16((a), (b), (c), 0, 0, 0)

__device__ __forceinline__ unsigned short f2b(float f) {
    union { float f; unsigned int u; } v; v.f = f;
    return (unsigned short)((v.u + 0x7FFFu + ((v.u >> 16) & 1u)) >> 16);
}
__device__ __forceinline__ float b2f(unsigned short b) {
    union { unsigned int u; float f; } v; v.u = ((unsigned int)b) << 16;
    return v.f;
}
__device__ __forceinline__ void fsplit(float x, unsigned short& hi, unsigned short& lo) {
    hi = f2b(x);
    lo = f2b(x - b2f(hi));
}

// ---------------------------------------------------------------------------
// pack_x: x [ROWS][170] f32 -> xh/xl [ROWS][192] split bf16 (zero-padded)
// ---------------------------------------------------------------------------
__global__ __launch_bounds__(256) void pack_x(
    const float* __restrict__ x,
    unsigned short* __restrict__ xh, unsigned short* __restrict__ xl)
{
    int idx = blockIdx.x * 256 + threadIdx.x;
    if (idx >= ROWS * KPAD) return;
    int r = idx / KPAD, c = idx % KPAD;
    float v = (c < INDIM) ? x[(size_t)r * INDIM + c] : 0.f;
    unsigned short hi, lo; fsplit(v, hi, lo);
    xh[idx] = hi; xl[idx] = lo;
}

// ---------------------------------------------------------------------------
// pack_w2: LDS-transpose weight pack (coalesced reads and writes).
// ---------------------------------------------------------------------------
__global__ __launch_bounds__(256) void pack_w2(
    const float* __restrict__ Wp, const float* __restrict__ Wq,
    const float* __restrict__ Wk, const float* __restrict__ Wv,
    const float* __restrict__ Wo,
    unsigned short* __restrict__ WpTh, unsigned short* __restrict__ WpTl,
    unsigned short* __restrict__ Wth,  unsigned short* __restrict__ Wtl)
{
    __shared__ float T[64][65];
    const int t = blockIdx.x, tid = threadIdx.x;

    if (t < 128) {
        const int l = t >> 6, rem = t & 63;
        const int kt = rem >> 4, nt = rem & 15;
        const int n0 = nt * 64;
        const int seg = n0 >> 8, ns0 = n0 & 255;
        const float* W = (seg == 0) ? Wq : (seg == 1) ? Wk : (seg == 2) ? Wv : Wo;
        #pragma unroll
        for (int p = 0; p < 16; p++) {
            const int idx = p * 256 + tid;
            const int r = idx >> 6, c = idx & 63;
            T[r][c] = W[(size_t)l * 65536 + (size_t)(kt * 64 + r) * 256 + ns0 + c];
        }
        __syncthreads();
        #pragma unroll
        for (int p = 0; p < 16; p++) {
            const int idx = p * 256 + tid;
            const int nl = idx >> 6, kl = idx & 63;
            unsigned short hi, lo; fsplit(T[kl][nl], hi, lo);
            const size_t d = (size_t)l * 1024 * 256 + (size_t)(n0 + nl) * 256 + kt * 64 + kl;
            Wth[d] = hi; Wtl[d] = lo;
        }
    } else {
        const int t2 = t - 128;
        const int kt = t2 % 3, nt = t2 / 3;
        #pragma unroll
        for (int p = 0; p < 16; p++) {
            const int idx = p * 256 + tid;
            const int r = idx >> 6, c = idx & 63;
            const int k = kt * 64 + r;
            T[r][c] = (k < INDIM) ? Wp[(size_t)k * HIDN + nt * 64 + c] : 0.f;
        }
        __syncthreads();
        #pragma unroll
        for (int p = 0; p < 16; p++) {
            const int idx = p * 256 + tid;
            const int nl = idx >> 6, kl = idx & 63;
            unsigned short hi, lo; fsplit(T[kl][nl], hi, lo);
            const size_t d = (size_t)(nt * 64 + nl) * KPAD + kt * 64 + kl;
            WpTh[d] = hi; WpTl[d] = lo;
        }
    }
}

// ---------------------------------------------------------------------------
// split-bf16 MFMA GEMM (3-product), input projection only.
// ---------------------------------------------------------------------------
__global__ __launch_bounds__(256) void gemm_mfma3(
    const unsigned short* __restrict__ Ah, const unsigned short* __restrict__ Al,
    const unsigned short* __restrict__ Bh, const unsigned short* __restrict__ Bl,
    const float* __restrict__ bias,
    unsigned short* __restrict__ c0, unsigned short* __restrict__ c1,
    int M, int N, int K)
{
    __shared__ unsigned short AsH[128 * 64];
    __shared__ unsigned short AsL[128 * 64];
    __shared__ unsigned short BsH[128 * 64];
    __shared__ unsigned short BsL[128 * 64];
    const int tid  = threadIdx.x;
    const int lane = tid & 63;
    const int wave = tid >> 6;
    const int wr = wave >> 1, wc = wave & 1;
    const int m0 = blockIdx.x * 128, n0 = blockIdx.y * 128;

    f32x4 acc[4][4] = {};

    for (int k0 = 0; k0 < K; k0 += 64) {
        #pragma unroll
        for (int j = 0; j < 4; j++) {
            int c   = j * 256 + tid;
            int row = c >> 3;
            int kcs = ((c & 7) ^ (row & 7)) * 8;
            size_t aoff = (size_t)(m0 + row) * K + k0 + kcs;
            size_t boff = (size_t)(n0 + row) * K + k0 + kcs;
            __builtin_amdgcn_global_load_lds(
                (const __attribute__((address_space(1))) void*)(Ah + aoff),
                (__attribute__((address_space(3))) void*)(AsH + c * 8), 16, 0, 0);
            __builtin_amdgcn_global_load_lds(
                (const __attribute__((address_space(1))) void*)(Al + aoff),
                (__attribute__((address_space(3))) void*)(AsL + c * 8), 16, 0, 0);
            __builtin_amdgcn_global_load_lds(
                (const __attribute__((address_space(1))) void*)(Bh + boff),
                (__attribute__((address_space(3))) void*)(BsH + c * 8), 16, 0, 0);
            __builtin_amdgcn_global_load_lds(
                (const __attribute__((address_space(1))) void*)(Bl + boff),
                (__attribute__((address_space(3))) void*)(BsL + c * 8), 16, 0, 0);
        }
        asm volatile("s_waitcnt vmcnt(0)" ::: "memory");
        __syncthreads();

        #pragma unroll
        for (int kk = 0; kk < 2; kk++) {
            bf16x8 ah[4], al[4], bh[4], bl[4];
            #pragma unroll
            for (int i = 0; i < 4; i++) {
                const int ar  = wr * 64 + i * 16 + (lane & 15);
                const int off = ar * 64 + (((kk * 4 + (lane >> 4)) ^ (ar & 7)) * 8);
                ah[i] = *(const bf16x8*)&AsH[off];
                al[i] = *(const bf16x8*)&AsL[off];
            }
            #pragma unroll
            for (int j = 0; j < 4; j++) {
                const int br  = wc * 64 + j * 16 + (lane & 15);
                const int off = br * 64 + (((kk * 4 + (lane >> 4)) ^ (br & 7)) * 8);
                bh[j] = *(const bf16x8*)&BsH[off];
                bl[j] = *(const bf16x8*)&BsL[off];
            }
            #pragma unroll
            for (int i = 0; i < 4; i++) {
                #pragma unroll
                for (int j = 0; j < 4; j++) {
                    acc[i][j] = MF(ah[i], bh[j], acc[i][j]);
                    acc[i][j] = MF(ah[i], bl[j], acc[i][j]);
                    acc[i][j] = MF(al[i], bh[j], acc[i][j]);
                }
            }
        }
        __syncthreads();
    }

    #pragma unroll
    for (int i = 0; i < 4; i++) {
        #pragma unroll
        for (int j = 0; j < 4; j++) {
            const int col = n0 + wc * 64 + j * 16 + (lane & 15);
            const float bv = bias[col];
            #pragma unroll
            for (int r = 0; r < 4; r++) {
                const int row = m0 + wr * 64 + i * 16 + (lane >> 4) * 4 + r;
                float v = acc[i][j][r] + bv;
                unsigned short hi, lo; fsplit(v, hi, lo);
                c0[(size_t)row * N + col] = hi;
                c1[(size_t)row * N + col] = lo;
            }
        }
    }
}

// ---------------------------------------------------------------------------
// i/f gate projection (layer 0 only). 4 waves, one row per wave.
// ---------------------------------------------------------------------------
__global__ __launch_bounds__(256) void ifproj(
    const unsigned short* __restrict__ hbh, const unsigned short* __restrict__ hbl,
    const float* __restrict__ wi, const float* __restrict__ wf,
    const float* __restrict__ bi, const float* __restrict__ bf,
    float* __restrict__ iout, float* __restrict__ fout)
{
    const int w    = threadIdx.x >> 6;
    const int lane = threadIdx.x & 63;
    const int row  = blockIdx.x * 4 + w;
    ushort4 a4 = *(const ushort4*)(hbh + (size_t)row * HIDN + lane * 4);
    ushort4 l4 = *(const ushort4*)(hbl + (size_t)row * HIDN + lane * 4);
    float yv[4];
    yv[0] = b2f(a4.x) + b2f(l4.x);
    yv[1] = b2f(a4.y) + b2f(l4.y);
    yv[2] = b2f(a4.z) + b2f(l4.z);
    yv[3] = b2f(a4.w) + b2f(l4.w);

    float g8[8] = {0.f,0.f,0.f,0.f,0.f,0.f,0.f,0.f};
    #pragma unroll
    for (int j = 0; j < 4; j++) {
        const float4 wiv = *(const float4*)(wi + (size_t)(lane * 4 + j) * 4);
        const float4 wfv = *(const float4*)(wf + (size_t)(lane * 4 + j) * 4);
        g8[0] += yv[j] * wiv.x; g8[1] += yv[j] * wiv.y;
        g8[2] += yv[j] * wiv.z; g8[3] += yv[j] * wiv.w;
        g8[4] += yv[j] * wfv.x; g8[5] += yv[j] * wfv.y;
        g8[6] += yv[j] * wfv.z; g8[7] += yv[j] * wfv.w;
    }
    #pragma unroll
    for (int o = 0; o < 8; o++)
        #pragma unroll
        for (int off = 32; off; off >>= 1) g8[o] += __shfl_xor(g8[o], off);
    if (lane < 4)      iout[(size_t)row * NH + lane] = g8[lane] + bi[lane];
    else if (lane < 8) fout[(size_t)row * NH + lane - 4] = g8[lane] + bf[lane - 4];
}

// ---------------------------------------------------------------------------
// FUSED layer kernel v10: block = (batch-PAIR bp, head hh) -> 512 blocks =
// ONE round at 2 blocks/CU. 8 waves; GEMM wave = (g = w>>2, seg = w&3):
// 64x64 tile, acc[4][4]. __launch_bounds__(512, 2): hipcc's 2nd arg is MIN
// BLOCKS/CU (CUDA semantics, established r10-r15) -> 2 blocks x 8 waves =
// 16 waves/CU -> 128-VGPR cap. Register diet: staging via 3 shared 32-bit
// element offsets against SGPR base pointers; ds_read bases + i*512 imms
// (swizzle i/j-invariant).
// LDS (shorts): staging Ah[0,4096) Al[4096,8192) Bh[8192,16384) Bl[16384,24576)
// Attn per batch (plain bf16): Ot f32 [0,8192) Qb@8192 Kb@12288 Tb@16384
//   Vb@20480 ; P@8192 stride 72 (overlays dead Q/K head, pre-P barrier);
//   denF f32x128 @ short 12800.
// ---------------------------------------------------------------------------
__global__ __launch_bounds__(512, 2) void fused_layer(
    const unsigned short* __restrict__ Ah, const unsigned short* __restrict__ Al,
    const unsigned short* __restrict__ Bh, const unsigned short* __restrict__ Bl,
    const float* __restrict__ bo,
    const float* __restrict__ irg, const float* __restrict__ frg,
    unsigned short* __restrict__ hoh, unsigned short* __restrict__ hol)
{
    extern __shared__ char smem[];
    unsigned short* const S = (unsigned short*)smem;
    float* const Ot   = (float*)smem;
    float* const denF = (float*)(S + 12800);

    const int bid  = blockIdx.x;
    const int xcd  = bid & 7;
    const int idx2 = bid >> 3;                 // 0..63
    const int hh   = idx2 & 3;
    const int bp   = xcd + 8 * (idx2 >> 2);    // batch-pair; 4 heads same XCD
    const int b0   = bp * 2;
    const int tid = threadIdx.x, lane = tid & 63, w = tid >> 6;
    const int g = w >> 2, seg = w & 3;

    // ---- staging: 3 shared 32-bit element offsets + LDS dsts ----
    const int rA  = tid >> 2, cpA = tid & 3;
    const int swA = (cpA ^ ((rA >> 1) & 3)) * 8;
    unsigned int aoff = (unsigned int)(bp * 128 + rA) * 256 + swA;
    const int d0 = rA * 32 + swA;
    const int rB1 = 128 + rA;
    const int gr0 = hh * 64 + (rA & 63) + ((rA >> 6) << 8);        // rows 0..127 -> segs 0,1
    const int gr1 = hh * 64 + (rB1 & 63) + ((rB1 >> 6) << 8);      // rows 128..255 -> segs 2,3
    unsigned int boff0 = (unsigned int)gr0 * 256 + swA;
    unsigned int boff1 = (unsigned int)gr1 * 256 + swA;
    const int d2 = rA * 32 + swA;               // B region row 0..127
    const int d3 = rB1 * 32 + swA;              // B region row 128..255

#define STAGE()                                                                \
    do {                                                                       \
        __builtin_amdgcn_global_load_lds(                                      \
            (const __attribute__((address_space(1))) void*)(Ah + aoff),        \
            (__attribute__((address_space(3))) void*)(S + d0), 16, 0, 0);      \
        __builtin_amdgcn_global_load_lds(                                      \
            (const __attribute__((address_space(1))) void*)(Al + aoff),        \
            (__attribute__((address_space(3))) void*)(S + 4096 + d0), 16, 0, 0); \
        __builtin_amdgcn_global_load_lds(                                      \
            (const __attribute__((address_space(1))) void*)(Bh + boff0),       \
            (__attribute__((address_space(3))) void*)(S + 8192 + d2), 16, 0, 0); \
        __builtin_amdgcn_global_load_lds(                                      \
            (const __attribute__((address_space(1))) void*)(Bh + boff1),       \
            (__attribute__((address_space(3))) void*)(S + 8192 + d3), 16, 0, 0); \
        __builtin_amdgcn_global_load_lds(                                      \
            (const __attribute__((address_space(1))) void*)(Bl + boff0),       \
            (__attribute__((address_space(3))) void*)(S + 16384 + d2), 16, 0, 0); \
        __builtin_amdgcn_global_load_lds(                                      \
            (const __attribute__((address_space(1))) void*)(Bl + boff1),       \
            (__attribute__((address_space(3))) void*)(S + 16384 + d3), 16, 0, 0); \
        aoff += 32; boff0 += 32; boff1 += 32;                                  \
    } while (0)

    // hoisted ds_read offset BASES; +i*512 / +j*512 fold to immediates
    // (swizzle term invariant: +16 rows adds 8 to r>>1, (r>>1)&3 unchanged)
    const int arB = g * 64 + (lane & 15);
    const int aob = arB * 32 + (((lane >> 4) ^ ((arB >> 1) & 3)) * 8);
    const int brB = seg * 64 + (lane & 15);
    const int bob = brB * 32 + (((lane >> 4) ^ ((brB >> 1) & 3)) * 8);

    // ---- GEMM phase: 8 serial BK=32 steps (cross-block TLP overlaps) ----
    f32x4 acc[4][4] = {};
    #pragma unroll
    for (int s = 0; s < 8; s++) {
        STAGE();
        asm volatile("s_waitcnt vmcnt(0)" ::: "memory");
        __syncthreads();

        __builtin_amdgcn_s_setprio(1);
        bf16x8 a_h[4], a_l[4];
        #pragma unroll
        for (int i = 0; i < 4; i++) {
            a_h[i] = *(const bf16x8*)&S[aob + i * 512];
            a_l[i] = *(const bf16x8*)&S[4096 + aob + i * 512];
        }
        #pragma unroll
        for (int j = 0; j < 4; j++) {
            const bf16x8 b_h = *(const bf16x8*)&S[8192 + bob + j * 512];
            const bf16x8 b_l = *(const bf16x8*)&S[16384 + bob + j * 512];
            #pragma unroll
            for (int i = 0; i < 4; i++) {
                acc[i][j] = MF(a_h[i], b_h, acc[i][j]);
                acc[i][j] = MF(a_h[i], b_l, acc[i][j]);
                acc[i][j] = MF(a_l[i], b_h, acc[i][j]);
            }
        }
        __builtin_amdgcn_s_setprio(0);
        __syncthreads();    // compute done before next stage overwrites
    }
#undef STAGE

    // gate prefix scans for the 2 batches (after GEMM)
    float sa2[2], sc2[2];
    #pragma unroll
    for (int gq = 0; gq < 2; gq++) {
        float iv = irg[(size_t)((b0 + gq) * TT + lane) * NH + hh];
        float fv = frg[(size_t)((b0 + gq) * TT + lane) * NH + hh];
        float F = fv;
        #pragma unroll
        for (int d2i = 1; d2i < 64; d2i <<= 1) { float o2 = __shfl_up(F, d2i); if (lane >= d2i) F += o2; }
        const float av = iv - F;
        float pm = av;
        #pragma unroll
        for (int d2i = 1; d2i < 64; d2i <<= 1) { float o2 = __shfl_up(pm, d2i); if (lane >= d2i) pm = fmaxf(pm, o2); }
        sa2[gq] = av;
        sc2[gq] = -fmaxf(0.f, pm);
    }

    // ---- attention: 2 batches sequentially (plain bf16 tiles) ----
    const int colb = lane & 15;
    const int rowb = (lane >> 4) * 4;
    const int tg = w & 3, sh = w >> 2;
    const int tA = tg * 16 + (lane & 15);
    const int tbase = tg * 16 + (lane >> 4) * 4;

    #pragma unroll
    for (int g2 = 0; g2 < 2; g2++) {
        const int bcur = b0 + g2;

        // scatter: only the 4 waves owning batch g2 write tiles
        if (g == g2) {
            #pragma unroll
            for (int i = 0; i < 4; i++) {
                #pragma unroll
                for (int j = 0; j < 4; j++) {
                    const int d = j * 16 + colb;
                    #pragma unroll
                    for (int r = 0; r < 4; r++) {
                        const int t = i * 16 + rowb + r;
                        float v = acc[i][j][r];
                        if (seg == 0) {                    // q * D^-1/2
                            const int idx = t * 64 + (d ^ ((t & 7) << 3));
                            S[8192 + idx] = f2b(v * 0.125f);
                        } else if (seg == 1) {             // k (+ transposed)
                            const unsigned short kb = f2b(v);
                            const int idx = t * 64 + (d ^ ((t & 7) << 3));
                            S[12288 + idx] = kb;
                            const int idx2b = d * 64 + (t ^ ((d & 7) << 3));
                            S[16384 + idx2b] = kb;
                        } else if (seg == 2) {             // v
                            const int idx = t * 64 + (d ^ ((t & 7) << 3));
                            S[20480 + idx] = f2b(v);
                        } else {                           // o = sigmoid, f32
                            Ot[t * 64 + d] = 1.f / (1.f + __expf(-(v + bo[hh * 64 + d])));
                        }
                    }
                }
            }
        }
        __syncthreads();

        // S phase
        f32x4 sv[2] = {}, sk[2] = {};
        #pragma unroll
        for (int kk = 0; kk < 2; kk++) {
            const int eA = (kk * 32 + (lane >> 4) * 8) ^ ((tA & 7) << 3);
            const bf16x8 aQ = *(const bf16x8*)&S[8192 + tA * 64 + eA];
            #pragma unroll
            for (int j = 0; j < 2; j++) {
                const int sB = sh * 32 + j * 16 + (lane & 15);
                const int eB = (kk * 32 + (lane >> 4) * 8) ^ ((sB & 7) << 3);
                const bf16x8 bK = *(const bf16x8*)&S[12288 + sB * 64 + eB];
                const bf16x8 bV = *(const bf16x8*)&S[20480 + sB * 64 + eB];
                sv[j] = MF(aQ, bV, sv[j]);
                sk[j] = MF(aQ, bK, sk[j]);
            }
        }

        // mask + half-denominator
        float cw[4], dh4[4] = {0.f, 0.f, 0.f, 0.f};
        #pragma unroll
        for (int r = 0; r < 4; r++) cw[r] = __shfl(sc2[g2], tbase + r);
        #pragma unroll
        for (int j = 0; j < 2; j++) {
            const int s = sh * 32 + j * 16 + (lane & 15);
            const float as = __shfl(sa2[g2], s);
            #pragma unroll
            for (int r = 0; r < 4; r++) {
                const int t = tbase + r;
                const float wgt = (s <= t) ? __expf(as + cw[r]) : 0.f;
                sv[j][r] *= wgt;
                dh4[r] += sk[j][r] * wgt;
            }
        }
        #pragma unroll
        for (int r = 0; r < 4; r++) {
            dh4[r] += __shfl_xor(dh4[r], 1);
            dh4[r] += __shfl_xor(dh4[r], 2);
            dh4[r] += __shfl_xor(dh4[r], 4);
            dh4[r] += __shfl_xor(dh4[r], 8);
        }

        __syncthreads();   // all S reads of Q/K done before P overlays them

        // write P (stride 72, overlays dead Q + head of K) + den halves
        #pragma unroll
        for (int j = 0; j < 2; j++) {
            const int s = sh * 32 + j * 16 + (lane & 15);
            #pragma unroll
            for (int r = 0; r < 4; r++) {
                const int t = tbase + r;
                S[8192 + t * 72 + s] = f2b(sv[j][r]);
            }
        }
        if ((lane & 15) == 0) {
            #pragma unroll
            for (int r = 0; r < 4; r++) denF[sh * 64 + tbase + r] = dh4[r];
        }
        __syncthreads();

        // PV phase: num = P @ K (B from KT tile)
        f32x4 num[2] = {};
        #pragma unroll
        for (int kk = 0; kk < 2; kk++) {
            const int sA2 = kk * 32 + (lane >> 4) * 8;
            const bf16x8 aP = *(const bf16x8*)&S[8192 + tA * 72 + sA2];
            #pragma unroll
            for (int j = 0; j < 2; j++) {
                const int e2 = sh * 32 + j * 16 + (lane & 15);
                const int tB = (kk * 32 + (lane >> 4) * 8) ^ ((e2 & 7) << 3);
                const bf16x8 bT = *(const bf16x8*)&S[16384 + e2 * 64 + tB];
                num[j] = MF(aP, bT, num[j]);
            }
        }

        // output: h = o * num / den -> split bf16
        #pragma unroll
        for (int j = 0; j < 2; j++) {
            const int e = sh * 32 + j * 16 + (lane & 15);
            #pragma unroll
            for (int r = 0; r < 4; r++) {
                const int t = tbase + r;
                const float den = fmaxf(fabsf(denF[t] + denF[64 + t]), 1.f);
                const float o = Ot[t * 64 + e];
                const float hval = o * num[j][r] / den;
                unsigned short hi, lo; fsplit(hval, hi, lo);
                const size_t oidx = (size_t)(bcur * TT + t) * HIDN + hh * DH + e;
                hoh[oidx] = hi; hol[oidx] = lo;
            }
        }
        __syncthreads();   // tiles/Ot/denF free before next batch's scatter
    }
}

// ---------------------------------------------------------------------------
// LayerNorm over 256 (+fused i/f gate projection for the NEXT layer).
// ---------------------------------------------------------------------------
__global__ __launch_bounds__(256) void layernorm_gate(
    const unsigned short* __restrict__ sh_, const unsigned short* __restrict__ sl_,
    unsigned short* __restrict__ dh_, unsigned short* __restrict__ dl_,
    const float* __restrict__ g, const float* __restrict__ bta,
    const float* __restrict__ wi, const float* __restrict__ wf,
    const float* __restrict__ bi, const float* __restrict__ bf,
    float* __restrict__ iout, float* __restrict__ fout)
{
    const int w    = threadIdx.x >> 6;
    const int lane = threadIdx.x & 63;
    const int row  = blockIdx.x * 4 + w;
    ushort4 a4 = *(const ushort4*)(sh_ + (size_t)row * HIDN + lane * 4);
    ushort4 l4 = *(const ushort4*)(sl_ + (size_t)row * HIDN + lane * 4);
    float x0 = b2f(a4.x) + b2f(l4.x);
    float x1 = b2f(a4.y) + b2f(l4.y);
    float x2 = b2f(a4.z) + b2f(l4.z);
    float x3 = b2f(a4.w) + b2f(l4.w);
    float s = x0 + x1 + x2 + x3;
    #pragma unroll
    for (int off = 32; off; off >>= 1) s += __shfl_xor(s, off);
    const float mu = s * (1.f / 256.f);
    const float d0 = x0 - mu, d1 = x1 - mu, d2 = x2 - mu, d3 = x3 - mu;
    float vs = d0*d0 + d1*d1 + d2*d2 + d3*d3;
    #pragma unroll
    for (int off = 32; off; off >>= 1) vs += __shfl_xor(vs, off);
    const float rstd = rsqrtf(vs * (1.f / 256.f) + EPS);
    const float4 gv = *(const float4*)(g + lane * 4);
    const float4 bv = *(const float4*)(bta + lane * 4);
    float yv[4];
    yv[0] = d0 * rstd * gv.x + bv.x;
    yv[1] = d1 * rstd * gv.y + bv.y;
    yv[2] = d2 * rstd * gv.z + bv.z;
    yv[3] = d3 * rstd * gv.w + bv.w;
    ushort4 h4, o4;
    fsplit(yv[0], h4.x, o4.x); fsplit(yv[1], h4.y, o4.y);
    fsplit(yv[2], h4.z, o4.z); fsplit(yv[3], h4.w, o4.w);
    *(ushort4*)(dh_ + (size_t)row * HIDN + lane * 4) = h4;
    *(ushort4*)(dl_ + (size_t)row * HIDN + lane * 4) = o4;

    float g8[8] = {0.f,0.f,0.f,0.f,0.f,0.f,0.f,0.f};
    #pragma unroll
    for (int j = 0; j < 4; j++) {
        const float4 wiv = *(const float4*)(wi + (size_t)(lane * 4 + j) * 4);
        const float4 wfv = *(const float4*)(wf + (size_t)(lane * 4 + j) * 4);
        g8[0] += yv[j] * wiv.x; g8[1] += yv[j] * wiv.y;
        g8[2] += yv[j] * wiv.z; g8[3] += yv[j] * wiv.w;
        g8[4] += yv[j] * wfv.x; g8[5] += yv[j] * wfv.y;
        g8[6] += yv[j] * wfv.z; g8[7] += yv[j] * wfv.w;
    }
    #pragma unroll
    for (int o = 0; o < 8; o++)
        #pragma unroll
        for (int off = 32; off; off >>= 1) g8[o] += __shfl_xor(g8[o], off);
    if (lane < 4)      iout[(size_t)row * NH + lane] = g8[lane] + bi[lane];
    else if (lane < 8) fout[(size_t)row * NH + lane - 4] = g8[lane] + bf[lane - 4];
}

// ---------------------------------------------------------------------------
// Final head with FUSED LayerNorm (only t = T-1 is consumed downstream).
// ---------------------------------------------------------------------------
__global__ __launch_bounds__(128) void head_ln_mlp(
    const unsigned short* __restrict__ h2h, const unsigned short* __restrict__ h2l,
    const float* __restrict__ g, const float* __restrict__ bta,
    const float* __restrict__ W1, const float* __restrict__ b1,
    const float* __restrict__ W2, const float* __restrict__ b2,
    float* __restrict__ out)
{
    const int b = blockIdx.x;
    const int j = threadIdx.x;
    const int wv = j >> 6, lane = j & 63;
    __shared__ float z[HIDN];
    __shared__ float a[128];
    __shared__ float red[4];
    const size_t rb = ((size_t)b * TT + (TT - 1)) * HIDN;
    const float x0 = b2f(h2h[rb + j])       + b2f(h2l[rb + j]);
    const float x1 = b2f(h2h[rb + j + 128]) + b2f(h2l[rb + j + 128]);
    float s = x0 + x1;
    #pragma unroll
    for (int off = 32; off; off >>= 1) s += __shfl_xor(s, off);
    if (lane == 0) red[wv] = s;
    __syncthreads();
    const float mu = (red[0] + red[1]) * (1.f / 256.f);
    const float dd0 = x0 - mu, dd1 = x1 - mu;
    float vs = dd0 * dd0 + dd1 * dd1;
    #pragma unroll
    for (int off = 32; off; off >>= 1) vs += __shfl_xor(vs, off);
    if (lane == 0) red[2 + wv] = vs;
    __syncthreads();
    const float rstd = rsqrtf((red[2] + red[3]) * (1.f / 256.f) + EPS);
    z[j]       = dd0 * rstd * g[j] + bta[j];
    z[j + 128] = dd1 * rstd * g[j + 128] + bta[j + 128];
    __syncthreads();
    float acc = b1[j];
    #pragma unroll 4
    for (int c = 0; c < HIDN; c++) acc += z[c] * W1[c * 128 + j];
    a[j] = fmaxf(acc, 0.f);
    __syncthreads();
    if (j < 2) {
        float sum = b2[j];
        for (int c = 0; c < 128; c++) sum += a[c] * W2[c * 2 + j];
        out[b * 2 + j] = sum;
    }
}

// ---------------------------------------------------------------------------
extern "C" void kernel_launch(void* const* d_in, const int* in_sizes, int n_in,
                              void* d_out, int out_size, void* d_ws, size_t ws_size,
                              hipStream_t stream)
{
    const float* x   = (const float*)d_in[0];
    const float* Wp  = (const float*)d_in[1];
    const float* bp  = (const float*)d_in[2];
    const float* Wq  = (const float*)d_in[3];
    const float* Wk  = (const float*)d_in[4];
    const float* Wv  = (const float*)d_in[5];
    const float* Wo  = (const float*)d_in[6];
    const float* bo  = (const float*)d_in[7];
    const float* wi  = (const float*)d_in[8];
    const float* bi  = (const float*)d_in[9];
    const float* wf  = (const float*)d_in[10];
    const float* bf  = (const float*)d_in[11];
    const float* lng = (const float*)d_in[12];
    const float* lnb = (const float*)d_in[13];
    const float* W1  = (const float*)d_in[14];
    const float* b1  = (const float*)d_in[15];
    const float* W2  = (const float*)d_in[16];
    const float* b2  = (const float*)d_in[17];
    float* out = (float*)d_out;

    // workspace layout (~37 MB)
    unsigned short* hbh = (unsigned short*)d_ws;            // [ROWS][256]
    unsigned short* hbl = hbh + (size_t)ROWS * HIDN;
    unsigned short* h2h = hbl + (size_t)ROWS * HIDN;        // fused-layer output
    unsigned short* h2l = h2h + (size_t)ROWS * HIDN;
    float*          ir  = (float*)(h2l + (size_t)ROWS * HIDN);
    float*          fr  = ir + (size_t)ROWS * NH;
    unsigned short* WpTh = (unsigned short*)(fr + (size_t)ROWS * NH);
    unsigned short* WpTl = WpTh + (size_t)HIDN * KPAD;
    unsigned short* Wth  = WpTl + (size_t)HIDN * KPAD;
    unsigned short* Wtl  = Wth + (size_t)2 * 1024 * 256;
    // pack_x outputs alias h2h/h2l (dead until first fused layer writes them)
    unsigned short* xh = h2h;
    unsigned short* xl = h2l;

    pack_x<<<(ROWS * KPAD + 255) / 256, 256, 0, stream>>>(x, xh, xl);
    pack_w2<<<140, 256, 0, stream>>>(Wp, Wq, Wk, Wv, Wo, WpTh, WpTl, Wth, Wtl);

    // input projection: hb = x @ Wp + bp (split)
    gemm_mfma3<<<dim3(128, 2), 256, 0, stream>>>(
        xh, xl, WpTh, WpTl, bp, hbh, hbl, ROWS, HIDN, KPAD);

    // layer-0 gates
    ifproj<<<ROWS / 4, 256, 0, stream>>>(hbh, hbl, wi, wf, bi, bf, ir, fr);

    // layer 0
    fused_layer<<<512, 512, 49152, stream>>>(
        hbh, hbl, Wth, Wtl, bo, ir, fr, h2h, h2l);
    // LN + layer-1 gates
    layernorm_gate<<<ROWS / 4, 256, 0, stream>>>(
        h2h, h2l, hbh, hbl, lng, lnb,
        wi + (size_t)HIDN * NH, wf + (size_t)HIDN * NH, bi + NH, bf + NH, ir, fr);

    // layer 1
    fused_layer<<<512, 512, 49152, stream>>>(
        hbh, hbl, Wth + (size_t)1024 * 256, Wtl + (size_t)1024 * 256,
        bo + HIDN, ir, fr, h2h, h2l);

    // final LN fused into the head (only t = T-1 is consumed)
    head_ln_mlp<<<BATCH, 128, 0, stream>>>(
        h2h, h2l, lng + HIDN, lnb + HIDN, W1, b1, W2, b2, out);
}

// Round 18
// 159.528 us; speedup vs baseline: 1.4673x; 1.4673x over previous
//
#include <hip/hip_runtime.h>
#include <math.h>

typedef __attribute__((ext_vector_type(4))) float f32x4;
typedef __attribute__((ext_vector_type(8))) short bf16x8;

constexpr int BATCH = 256;
constexpr int TT    = 64;
constexpr int NH    = 4;
constexpr int DH    = 64;
constexpr int HIDN  = 256;
constexpr int INDIM = 170;
constexpr int KPAD  = 192;
constexpr int ROWS  = BATCH * TT;    // 16384
constexpr float EPS = 1e-5f;

#define MF(a, b, c) __builtin_amdgcn_mfma_f32_16x16x32_bf16((a), (b), (c), 0, 0, 0)

__device__ __forceinline__ unsigned short f2b(float f) {
    union { float f; unsigned int u; } v; v.f = f;
    return (unsigned short)((v.u + 0x7FFFu + ((v.u >> 16) & 1u)) >> 16);
}
__device__ __forceinline__ float b2f(unsigned short b) {
    union { unsigned int u; float f; } v; v.u = ((unsigned int)b) << 16;
    return v.f;
}
__device__ __forceinline__ void fsplit(float x, unsigned short& hi, unsigned short& lo) {
    hi = f2b(x);
    lo = f2b(x - b2f(hi));
}

// ---------------------------------------------------------------------------
// pack_x: x [ROWS][170] f32 -> xh/xl [ROWS][192] split bf16 (zero-padded)
// ---------------------------------------------------------------------------
__global__ __launch_bounds__(256) void pack_x(
    const float* __restrict__ x,
    unsigned short* __restrict__ xh, unsigned short* __restrict__ xl)
{
    int idx = blockIdx.x * 256 + threadIdx.x;
    if (idx >= ROWS * KPAD) return;
    int r = idx / KPAD, c = idx % KPAD;
    float v = (c < INDIM) ? x[(size_t)r * INDIM + c] : 0.f;
    unsigned short hi, lo; fsplit(v, hi, lo);
    xh[idx] = hi; xl[idx] = lo;
}

// ---------------------------------------------------------------------------
// pack_w2: LDS-transpose weight pack (coalesced reads and writes).
// ---------------------------------------------------------------------------
__global__ __launch_bounds__(256) void pack_w2(
    const float* __restrict__ Wp, const float* __restrict__ Wq,
    const float* __restrict__ Wk, const float* __restrict__ Wv,
    const float* __restrict__ Wo,
    unsigned short* __restrict__ WpTh, unsigned short* __restrict__ WpTl,
    unsigned short* __restrict__ Wth,  unsigned short* __restrict__ Wtl)
{
    __shared__ float T[64][65];
    const int t = blockIdx.x, tid = threadIdx.x;

    if (t < 128) {
        const int l = t >> 6, rem = t & 63;
        const int kt = rem >> 4, nt = rem & 15;
        const int n0 = nt * 64;
        const int seg = n0 >> 8, ns0 = n0 & 255;
        const float* W = (seg == 0) ? Wq : (seg == 1) ? Wk : (seg == 2) ? Wv : Wo;
        #pragma unroll
        for (int p = 0; p < 16; p++) {
            const int idx = p * 256 + tid;
            const int r = idx >> 6, c = idx & 63;
            T[r][c] = W[(size_t)l * 65536 + (size_t)(kt * 64 + r) * 256 + ns0 + c];
        }
        __syncthreads();
        #pragma unroll
        for (int p = 0; p < 16; p++) {
            const int idx = p * 256 + tid;
            const int nl = idx >> 6, kl = idx & 63;
            unsigned short hi, lo; fsplit(T[kl][nl], hi, lo);
            const size_t d = (size_t)l * 1024 * 256 + (size_t)(n0 + nl) * 256 + kt * 64 + kl;
            Wth[d] = hi; Wtl[d] = lo;
        }
    } else {
        const int t2 = t - 128;
        const int kt = t2 % 3, nt = t2 / 3;
        #pragma unroll
        for (int p = 0; p < 16; p++) {
            const int idx = p * 256 + tid;
            const int r = idx >> 6, c = idx & 63;
            const int k = kt * 64 + r;
            T[r][c] = (k < INDIM) ? Wp[(size_t)k * HIDN + nt * 64 + c] : 0.f;
        }
        __syncthreads();
        #pragma unroll
        for (int p = 0; p < 16; p++) {
            const int idx = p * 256 + tid;
            const int nl = idx >> 6, kl = idx & 63;
            unsigned short hi, lo; fsplit(T[kl][nl], hi, lo);
            const size_t d = (size_t)(nt * 64 + nl) * KPAD + kt * 64 + kl;
            WpTh[d] = hi; WpTl[d] = lo;
        }
    }
}

// ---------------------------------------------------------------------------
// split-bf16 MFMA GEMM (3-product), input projection only.
// ---------------------------------------------------------------------------
__global__ __launch_bounds__(256) void gemm_mfma3(
    const unsigned short* __restrict__ Ah, const unsigned short* __restrict__ Al,
    const unsigned short* __restrict__ Bh, const unsigned short* __restrict__ Bl,
    const float* __restrict__ bias,
    unsigned short* __restrict__ c0, unsigned short* __restrict__ c1,
    int M, int N, int K)
{
    __shared__ unsigned short AsH[128 * 64];
    __shared__ unsigned short AsL[128 * 64];
    __shared__ unsigned short BsH[128 * 64];
    __shared__ unsigned short BsL[128 * 64];
    const int tid  = threadIdx.x;
    const int lane = tid & 63;
    const int wave = tid >> 6;
    const int wr = wave >> 1, wc = wave & 1;
    const int m0 = blockIdx.x * 128, n0 = blockIdx.y * 128;

    f32x4 acc[4][4] = {};

    for (int k0 = 0; k0 < K; k0 += 64) {
        #pragma unroll
        for (int j = 0; j < 4; j++) {
            int c   = j * 256 + tid;
            int row = c >> 3;
            int kcs = ((c & 7) ^ (row & 7)) * 8;
            size_t aoff = (size_t)(m0 + row) * K + k0 + kcs;
            size_t boff = (size_t)(n0 + row) * K + k0 + kcs;
            __builtin_amdgcn_global_load_lds(
                (const __attribute__((address_space(1))) void*)(Ah + aoff),
                (__attribute__((address_space(3))) void*)(AsH + c * 8), 16, 0, 0);
            __builtin_amdgcn_global_load_lds(
                (const __attribute__((address_space(1))) void*)(Al + aoff),
                (__attribute__((address_space(3))) void*)(AsL + c * 8), 16, 0, 0);
            __builtin_amdgcn_global_load_lds(
                (const __attribute__((address_space(1))) void*)(Bh + boff),
                (__attribute__((address_space(3))) void*)(BsH + c * 8), 16, 0, 0);
            __builtin_amdgcn_global_load_lds(
                (const __attribute__((address_space(1))) void*)(Bl + boff),
                (__attribute__((address_space(3))) void*)(BsL + c * 8), 16, 0, 0);
        }
        asm volatile("s_waitcnt vmcnt(0)" ::: "memory");
        __syncthreads();

        #pragma unroll
        for (int kk = 0; kk < 2; kk++) {
            bf16x8 ah[4], al[4], bh[4], bl[4];
            #pragma unroll
            for (int i = 0; i < 4; i++) {
                const int ar  = wr * 64 + i * 16 + (lane & 15);
                const int off = ar * 64 + (((kk * 4 + (lane >> 4)) ^ (ar & 7)) * 8);
                ah[i] = *(const bf16x8*)&AsH[off];
                al[i] = *(const bf16x8*)&AsL[off];
            }
            #pragma unroll
            for (int j = 0; j < 4; j++) {
                const int br  = wc * 64 + j * 16 + (lane & 15);
                const int off = br * 64 + (((kk * 4 + (lane >> 4)) ^ (br & 7)) * 8);
                bh[j] = *(const bf16x8*)&BsH[off];
                bl[j] = *(const bf16x8*)&BsL[off];
            }
            #pragma unroll
            for (int i = 0; i < 4; i++) {
                #pragma unroll
                for (int j = 0; j < 4; j++) {
                    acc[i][j] = MF(ah[i], bh[j], acc[i][j]);
                    acc[i][j] = MF(ah[i], bl[j], acc[i][j]);
                    acc[i][j] = MF(al[i], bh[j], acc[i][j]);
                }
            }
        }
        __syncthreads();
    }

    #pragma unroll
    for (int i = 0; i < 4; i++) {
        #pragma unroll
        for (int j = 0; j < 4; j++) {
            const int col = n0 + wc * 64 + j * 16 + (lane & 15);
            const float bv = bias[col];
            #pragma unroll
            for (int r = 0; r < 4; r++) {
                const int row = m0 + wr * 64 + i * 16 + (lane >> 4) * 4 + r;
                float v = acc[i][j][r] + bv;
                unsigned short hi, lo; fsplit(v, hi, lo);
                c0[(size_t)row * N + col] = hi;
                c1[(size_t)row * N + col] = lo;
            }
        }
    }
}

// ---------------------------------------------------------------------------
// i/f gate projection (layer 0 only). 4 waves, one row per wave.
// ---------------------------------------------------------------------------
__global__ __launch_bounds__(256) void ifproj(
    const unsigned short* __restrict__ hbh, const unsigned short* __restrict__ hbl,
    const float* __restrict__ wi, const float* __restrict__ wf,
    const float* __restrict__ bi, const float* __restrict__ bf,
    float* __restrict__ iout, float* __restrict__ fout)
{
    const int w    = threadIdx.x >> 6;
    const int lane = threadIdx.x & 63;
    const int row  = blockIdx.x * 4 + w;
    ushort4 a4 = *(const ushort4*)(hbh + (size_t)row * HIDN + lane * 4);
    ushort4 l4 = *(const ushort4*)(hbl + (size_t)row * HIDN + lane * 4);
    float yv[4];
    yv[0] = b2f(a4.x) + b2f(l4.x);
    yv[1] = b2f(a4.y) + b2f(l4.y);
    yv[2] = b2f(a4.z) + b2f(l4.z);
    yv[3] = b2f(a4.w) + b2f(l4.w);

    float g8[8] = {0.f,0.f,0.f,0.f,0.f,0.f,0.f,0.f};
    #pragma unroll
    for (int j = 0; j < 4; j++) {
        const float4 wiv = *(const float4*)(wi + (size_t)(lane * 4 + j) * 4);
        const float4 wfv = *(const float4*)(wf + (size_t)(lane * 4 + j) * 4);
        g8[0] += yv[j] * wiv.x; g8[1] += yv[j] * wiv.y;
        g8[2] += yv[j] * wiv.z; g8[3] += yv[j] * wiv.w;
        g8[4] += yv[j] * wfv.x; g8[5] += yv[j] * wfv.y;
        g8[6] += yv[j] * wfv.z; g8[7] += yv[j] * wfv.w;
    }
    #pragma unroll
    for (int o = 0; o < 8; o++)
        #pragma unroll
        for (int off = 32; off; off >>= 1) g8[o] += __shfl_xor(g8[o], off);
    if (lane < 4)      iout[(size_t)row * NH + lane] = g8[lane] + bi[lane];
    else if (lane < 8) fout[(size_t)row * NH + lane - 4] = g8[lane] + bf[lane - 4];
}

// ---------------------------------------------------------------------------
// FUSED layer kernel v8 (r14 config, proven 48.1 us): 8 waves, one block per
// (b,h), 80 KiB dynamic LDS (2 blocks/CU, LDS-limited). BK=32 double-buffered
// pipeline, hoisted staging addresses + ds_read offsets, s_setprio around
// MFMA. __launch_bounds__(512,2): min-2-blocks/CU -> 128-VGPR cap (scheduler
// headroom; occupancy unchanged, LDS-limited at 2).
// Staging LDS (shorts), buffer p at p*20480: AH +0 AL +2048 BH +4096 BL +12288
// 64B-row swizzle: phys chunk = logical chunk ^ ((row>>1)&3).
// Attn tiles (plain bf16) overlay dead staging after GEMM:
//   Ot f32 [0,8192) Qb@8192 Kb@12288 Tb@16384 Vb@20480
//   P @24576 (stride 72, non-aliasing) ; denF f32x128 @ short 29184.
// ---------------------------------------------------------------------------
__global__ __launch_bounds__(512, 2) void fused_layer(
    const unsigned short* __restrict__ Ah, const unsigned short* __restrict__ Al,
    const unsigned short* __restrict__ Bh, const unsigned short* __restrict__ Bl,
    const float* __restrict__ bo,
    const float* __restrict__ irg, const float* __restrict__ frg,
    unsigned short* __restrict__ hoh, unsigned short* __restrict__ hol)
{
    extern __shared__ char smem[];
    unsigned short* const S = (unsigned short*)smem;
    float* const Ot   = (float*)smem;
    float* const denF = (float*)(S + 29184);

    const int n0  = blockIdx.x;
    const int mm  = n0 >> 3;
    const int hh  = mm & 3;
    const int b   = (n0 & 7) + 8 * (mm >> 2);      // 4 heads of b -> same XCD
    const int tid = threadIdx.x, lane = tid & 63, w = tid >> 6;

    // gate prefix scans, in registers (redundant per wave)
    float iv = irg[(size_t)(b * TT + lane) * NH + hh];
    float fv = frg[(size_t)(b * TT + lane) * NH + hh];
    float F = fv;
    #pragma unroll
    for (int d2 = 1; d2 < 64; d2 <<= 1) { float o2 = __shfl_up(F, d2); if (lane >= d2) F += o2; }
    const float sa_r = iv - F;                     // a_t = i_t - F_t
    float pm = sa_r;
    #pragma unroll
    for (int d2 = 1; d2 < 64; d2 <<= 1) { float o2 = __shfl_up(pm, d2); if (lane >= d2) pm = fmaxf(pm, o2); }
    const float sc_r = -fmaxf(0.f, pm);            // F_t - m_t

    const int wm = w >> 2, wn = w & 3;

    // ---- hoisted staging addresses: 5 (globalptr, ldsoff) pairs/thread ----
    const unsigned short* sptr0; const unsigned short* sptr1;
    const unsigned short* sptr2; const unsigned short* sptr3;
    const unsigned short* sptr4;
    int sdst0, sdst1, sdst2, sdst3, sdst4;
    {
        {
            const int hl = tid >> 8, c = tid & 255;
            const int r = c >> 2, cp = c & 3;
            const int col = (cp ^ ((r >> 1) & 3)) * 8;
            sptr0 = (hl ? Al : Ah) + (size_t)(b * TT + r) * 256 + col;
            sdst0 = hl * 2048 + c * 8;
        }
        #pragma unroll
        for (int rr = 0; rr < 4; rr++) {
            const int c2 = rr * 512 + tid;
            const int hl = c2 >> 10, c = c2 & 1023;
            const int r = c >> 2, cp = c & 3;
            const int grow = (r >> 6) * 256 + hh * 64 + (r & 63);
            const int col = (cp ^ ((r >> 1) & 3)) * 8;
            const unsigned short* p = (hl ? Bl : Bh) + (size_t)grow * 256 + col;
            const int d = 4096 + hl * 8192 + c * 8;
            if (rr == 0) { sptr1 = p; sdst1 = d; }
            else if (rr == 1) { sptr2 = p; sdst2 = d; }
            else if (rr == 2) { sptr3 = p; sdst3 = d; }
            else { sptr4 = p; sdst4 = d; }
        }
    }

#define STAGE(bs)                                                              \
    do {                                                                       \
        __builtin_amdgcn_global_load_lds(                                      \
            (const __attribute__((address_space(1))) void*)sptr0,              \
            (__attribute__((address_space(3))) void*)(S + (bs) + sdst0), 16, 0, 0); \
        __builtin_amdgcn_global_load_lds(                                      \
            (const __attribute__((address_space(1))) void*)sptr1,              \
            (__attribute__((address_space(3))) void*)(S + (bs) + sdst1), 16, 0, 0); \
        __builtin_amdgcn_global_load_lds(                                      \
            (const __attribute__((address_space(1))) void*)sptr2,              \
            (__attribute__((address_space(3))) void*)(S + (bs) + sdst2), 16, 0, 0); \
        __builtin_amdgcn_global_load_lds(                                      \
            (const __attribute__((address_space(1))) void*)sptr3,              \
            (__attribute__((address_space(3))) void*)(S + (bs) + sdst3), 16, 0, 0); \
        __builtin_amdgcn_global_load_lds(                                      \
            (const __attribute__((address_space(1))) void*)sptr4,              \
            (__attribute__((address_space(3))) void*)(S + (bs) + sdst4), 16, 0, 0); \
        sptr0 += 32; sptr1 += 32; sptr2 += 32; sptr3 += 32; sptr4 += 32;       \
    } while (0)

    // hoisted ds_read offsets (buffer-relative)
    int aoff_[2], boff_[4];
    #pragma unroll
    for (int i = 0; i < 2; i++) {
        const int ar = wm * 32 + i * 16 + (lane & 15);
        aoff_[i] = ar * 32 + (((lane >> 4) ^ ((ar >> 1) & 3)) * 8);
    }
    #pragma unroll
    for (int j = 0; j < 4; j++) {
        const int br = wn * 64 + j * 16 + (lane & 15);
        boff_[j] = br * 32 + (((lane >> 4) ^ ((br >> 1) & 3)) * 8);
    }

    // ---- GEMM phase: 8 pipelined BK=32 steps ----
    STAGE(0);
    asm volatile("s_waitcnt vmcnt(0)" ::: "memory");
    __syncthreads();

    f32x4 acc[2][4] = {};
    #pragma unroll
    for (int s = 0; s < 8; s++) {
        if (s < 7) STAGE(((s + 1) & 1) * 20480);

        const int pb = (s & 1) * 20480;
        __builtin_amdgcn_s_setprio(1);
        bf16x8 a_h[2], a_l[2], b_h[4], b_l[4];
        #pragma unroll
        for (int i = 0; i < 2; i++) {
            a_h[i] = *(const bf16x8*)&S[pb + aoff_[i]];
            a_l[i] = *(const bf16x8*)&S[pb + 2048 + aoff_[i]];
        }
        #pragma unroll
        for (int j = 0; j < 4; j++) {
            b_h[j] = *(const bf16x8*)&S[pb + 4096 + boff_[j]];
            b_l[j] = *(const bf16x8*)&S[pb + 12288 + boff_[j]];
        }
        #pragma unroll
        for (int i = 0; i < 2; i++) {
            #pragma unroll
            for (int j = 0; j < 4; j++) {
                acc[i][j] = MF(a_h[i], b_h[j], acc[i][j]);
                acc[i][j] = MF(a_h[i], b_l[j], acc[i][j]);
                acc[i][j] = MF(a_l[i], b_h[j], acc[i][j]);
            }
        }
        __builtin_amdgcn_s_setprio(0);
        if (s < 7) {
            asm volatile("s_waitcnt vmcnt(0)" ::: "memory");
            __syncthreads();
        }
    }
    __syncthreads();   // all waves done with staging buffers
#undef STAGE

    // ---- epilogue: scatter q/k/kt/v/o into PLAIN bf16 tiles + f32 Ot ----
    const int colb = lane & 15;
    const int rowb = (lane >> 4) * 4;
    #pragma unroll
    for (int i = 0; i < 2; i++) {
        #pragma unroll
        for (int j = 0; j < 4; j++) {
            const int d = j * 16 + colb;
            #pragma unroll
            for (int r = 0; r < 4; r++) {
                const int t = wm * 32 + i * 16 + rowb + r;
                float v = acc[i][j][r];
                if (wn == 0) {                     // q * D^-1/2
                    const int idx = t * 64 + (d ^ ((t & 7) << 3));
                    S[8192 + idx] = f2b(v * 0.125f);
                } else if (wn == 1) {              // k (+ transposed copy)
                    const unsigned short kb = f2b(v);
                    const int idx = t * 64 + (d ^ ((t & 7) << 3));
                    S[12288 + idx] = kb;
                    const int idx2 = d * 64 + (t ^ ((d & 7) << 3));
                    S[16384 + idx2] = kb;
                } else if (wn == 2) {              // v
                    const int idx = t * 64 + (d ^ ((t & 7) << 3));
                    S[20480 + idx] = f2b(v);
                } else {                           // o = sigmoid(.+bo), f32
                    Ot[t * 64 + d] = 1.f / (1.f + __expf(-(v + bo[hh * 64 + d])));
                }
            }
        }
    }
    __syncthreads();

    // ---- S phase: wave (tg = w&3) t-rows [16tg,+16), (sh = w>>2) s-half ----
    const int tg = w & 3, sh = w >> 2;
    f32x4 sv[2] = {}, sk[2] = {};
    const int tA = tg * 16 + (lane & 15);
    #pragma unroll
    for (int kk = 0; kk < 2; kk++) {
        const int eA = (kk * 32 + (lane >> 4) * 8) ^ ((tA & 7) << 3);
        const bf16x8 aQ = *(const bf16x8*)&S[8192 + tA * 64 + eA];
        #pragma unroll
        for (int j = 0; j < 2; j++) {
            const int sB = sh * 32 + j * 16 + (lane & 15);
            const int eB = (kk * 32 + (lane >> 4) * 8) ^ ((sB & 7) << 3);
            const bf16x8 bK = *(const bf16x8*)&S[12288 + sB * 64 + eB];
            const bf16x8 bV = *(const bf16x8*)&S[20480 + sB * 64 + eB];
            sv[j] = MF(aQ, bV, sv[j]);
            sk[j] = MF(aQ, bK, sk[j]);
        }
    }

    // mask + half-denominator
    const int tbase = tg * 16 + (lane >> 4) * 4;
    float cw[4], dh4[4] = {0.f, 0.f, 0.f, 0.f};
    #pragma unroll
    for (int r = 0; r < 4; r++) cw[r] = __shfl(sc_r, tbase + r);
    #pragma unroll
    for (int j = 0; j < 2; j++) {
        const int s = sh * 32 + j * 16 + (lane & 15);
        const float as = __shfl(sa_r, s);
        #pragma unroll
        for (int r = 0; r < 4; r++) {
            const int t = tbase + r;
            const float wgt = (s <= t) ? __expf(as + cw[r]) : 0.f;
            sv[j][r] *= wgt;
            dh4[r] += sk[j][r] * wgt;
        }
    }
    #pragma unroll
    for (int r = 0; r < 4; r++) {
        dh4[r] += __shfl_xor(dh4[r], 1);
        dh4[r] += __shfl_xor(dh4[r], 2);
        dh4[r] += __shfl_xor(dh4[r], 4);
        dh4[r] += __shfl_xor(dh4[r], 8);
    }

    // write P (own non-aliasing region, stride 72) + den halves
    #pragma unroll
    for (int j = 0; j < 2; j++) {
        const int s = sh * 32 + j * 16 + (lane & 15);
        #pragma unroll
        for (int r = 0; r < 4; r++) {
            const int t = tbase + r;
            S[24576 + t * 72 + s] = f2b(sv[j][r]);
        }
    }
    if ((lane & 15) == 0) {
        #pragma unroll
        for (int r = 0; r < 4; r++) denF[sh * 64 + tbase + r] = dh4[r];
    }
    __syncthreads();

    // ---- PV phase: num = P @ K (B from KT tile); wave (tg, eh=sh) ----
    f32x4 num[2] = {};
    #pragma unroll
    for (int kk = 0; kk < 2; kk++) {
        const int sA2 = kk * 32 + (lane >> 4) * 8;
        const bf16x8 aP = *(const bf16x8*)&S[24576 + tA * 72 + sA2];
        #pragma unroll
        for (int j = 0; j < 2; j++) {
            const int e2 = sh * 32 + j * 16 + (lane & 15);
            const int tB = (kk * 32 + (lane >> 4) * 8) ^ ((e2 & 7) << 3);
            const bf16x8 bT = *(const bf16x8*)&S[16384 + e2 * 64 + tB];
            num[j] = MF(aP, bT, num[j]);
        }
    }

    // ---- output: h = o * num / den -> split bf16 ----
    #pragma unroll
    for (int j = 0; j < 2; j++) {
        const int e = sh * 32 + j * 16 + (lane & 15);
        #pragma unroll
        for (int r = 0; r < 4; r++) {
            const int t = tbase + r;
            const float den = fmaxf(fabsf(denF[t] + denF[64 + t]), 1.f);
            const float o = Ot[t * 64 + e];
            const float hval = o * num[j][r] / den;
            unsigned short hi, lo; fsplit(hval, hi, lo);
            const size_t oidx = (size_t)(b * TT + t) * HIDN + hh * DH + e;
            hoh[oidx] = hi; hol[oidx] = lo;
        }
    }
}

// ---------------------------------------------------------------------------
// LayerNorm over 256 + fused i/f gate projection for the NEXT layer.
// ---------------------------------------------------------------------------
__global__ __launch_bounds__(256) void layernorm_gate(
    const unsigned short* __restrict__ sh_, const unsigned short* __restrict__ sl_,
    unsigned short* __restrict__ dh_, unsigned short* __restrict__ dl_,
    const float* __restrict__ g, const float* __restrict__ bta,
    const float* __restrict__ wi, const float* __restrict__ wf,
    const float* __restrict__ bi, const float* __restrict__ bf,
    float* __restrict__ iout, float* __restrict__ fout)
{
    const int w    = threadIdx.x >> 6;
    const int lane = threadIdx.x & 63;
    const int row  = blockIdx.x * 4 + w;
    ushort4 a4 = *(const ushort4*)(sh_ + (size_t)row * HIDN + lane * 4);
    ushort4 l4 = *(const ushort4*)(sl_ + (size_t)row * HIDN + lane * 4);
    float x0 = b2f(a4.x) + b2f(l4.x);
    float x1 = b2f(a4.y) + b2f(l4.y);
    float x2 = b2f(a4.z) + b2f(l4.z);
    float x3 = b2f(a4.w) + b2f(l4.w);
    float s = x0 + x1 + x2 + x3;
    #pragma unroll
    for (int off = 32; off; off >>= 1) s += __shfl_xor(s, off);
    const float mu = s * (1.f / 256.f);
    const float d0 = x0 - mu, d1 = x1 - mu, d2 = x2 - mu, d3 = x3 - mu;
    float vs = d0*d0 + d1*d1 + d2*d2 + d3*d3;
    #pragma unroll
    for (int off = 32; off; off >>= 1) vs += __shfl_xor(vs, off);
    const float rstd = rsqrtf(vs * (1.f / 256.f) + EPS);
    const float4 gv = *(const float4*)(g + lane * 4);
    const float4 bv = *(const float4*)(bta + lane * 4);
    float yv[4];
    yv[0] = d0 * rstd * gv.x + bv.x;
    yv[1] = d1 * rstd * gv.y + bv.y;
    yv[2] = d2 * rstd * gv.z + bv.z;
    yv[3] = d3 * rstd * gv.w + bv.w;
    ushort4 h4, o4;
    fsplit(yv[0], h4.x, o4.x); fsplit(yv[1], h4.y, o4.y);
    fsplit(yv[2], h4.z, o4.z); fsplit(yv[3], h4.w, o4.w);
    *(ushort4*)(dh_ + (size_t)row * HIDN + lane * 4) = h4;
    *(ushort4*)(dl_ + (size_t)row * HIDN + lane * 4) = o4;

    float g8[8] = {0.f,0.f,0.f,0.f,0.f,0.f,0.f,0.f};
    #pragma unroll
    for (int j = 0; j < 4; j++) {
        const float4 wiv = *(const float4*)(wi + (size_t)(lane * 4 + j) * 4);
        const float4 wfv = *(const float4*)(wf + (size_t)(lane * 4 + j) * 4);
        g8[0] += yv[j] * wiv.x; g8[1] += yv[j] * wiv.y;
        g8[2] += yv[j] * wiv.z; g8[3] += yv[j] * wiv.w;
        g8[4] += yv[j] * wfv.x; g8[5] += yv[j] * wfv.y;
        g8[6] += yv[j] * wfv.z; g8[7] += yv[j] * wfv.w;
    }
    #pragma unroll
    for (int o = 0; o < 8; o++)
        #pragma unroll
        for (int off = 32; off; off >>= 1) g8[o] += __shfl_xor(g8[o], off);
    if (lane < 4)      iout[(size_t)row * NH + lane] = g8[lane] + bi[lane];
    else if (lane < 8) fout[(size_t)row * NH + lane - 4] = g8[lane] + bf[lane - 4];
}

// ---------------------------------------------------------------------------
// Final head with FUSED LayerNorm (only t = T-1 is consumed downstream;
// validated numerically in round 15).
// ---------------------------------------------------------------------------
__global__ __launch_bounds__(128) void head_ln_mlp(
    const unsigned short* __restrict__ h2h, const unsigned short* __restrict__ h2l,
    const float* __restrict__ g, const float* __restrict__ bta,
    const float* __restrict__ W1, const float* __restrict__ b1,
    const float* __restrict__ W2, const float* __restrict__ b2,
    float* __restrict__ out)
{
    const int b = blockIdx.x;
    const int j = threadIdx.x;
    const int wv = j >> 6, lane = j & 63;
    __shared__ float z[HIDN];
    __shared__ float a[128];
    __shared__ float red[4];
    const size_t rb = ((size_t)b * TT + (TT - 1)) * HIDN;
    const float x0 = b2f(h2h[rb + j])       + b2f(h2l[rb + j]);
    const float x1 = b2f(h2h[rb + j + 128]) + b2f(h2l[rb + j + 128]);
    float s = x0 + x1;
    #pragma unroll
    for (int off = 32; off; off >>= 1) s += __shfl_xor(s, off);
    if (lane == 0) red[wv] = s;
    __syncthreads();
    const float mu = (red[0] + red[1]) * (1.f / 256.f);
    const float dd0 = x0 - mu, dd1 = x1 - mu;
    float vs = dd0 * dd0 + dd1 * dd1;
    #pragma unroll
    for (int off = 32; off; off >>= 1) vs += __shfl_xor(vs, off);
    if (lane == 0) red[2 + wv] = vs;
    __syncthreads();
    const float rstd = rsqrtf((red[2] + red[3]) * (1.f / 256.f) + EPS);
    z[j]       = dd0 * rstd * g[j] + bta[j];
    z[j + 128] = dd1 * rstd * g[j + 128] + bta[j + 128];
    __syncthreads();
    float acc = b1[j];
    #pragma unroll 4
    for (int c = 0; c < HIDN; c++) acc += z[c] * W1[c * 128 + j];
    a[j] = fmaxf(acc, 0.f);
    __syncthreads();
    if (j < 2) {
        float sum = b2[j];
        for (int c = 0; c < 128; c++) sum += a[c] * W2[c * 2 + j];
        out[b * 2 + j] = sum;
    }
}

// ---------------------------------------------------------------------------
extern "C" void kernel_launch(void* const* d_in, const int* in_sizes, int n_in,
                              void* d_out, int out_size, void* d_ws, size_t ws_size,
                              hipStream_t stream)
{
    const float* x   = (const float*)d_in[0];
    const float* Wp  = (const float*)d_in[1];
    const float* bp  = (const float*)d_in[2];
    const float* Wq  = (const float*)d_in[3];
    const float* Wk  = (const float*)d_in[4];
    const float* Wv  = (const float*)d_in[5];
    const float* Wo  = (const float*)d_in[6];
    const float* bo  = (const float*)d_in[7];
    const float* wi  = (const float*)d_in[8];
    const float* bi  = (const float*)d_in[9];
    const float* wf  = (const float*)d_in[10];
    const float* bf  = (const float*)d_in[11];
    const float* lng = (const float*)d_in[12];
    const float* lnb = (const float*)d_in[13];
    const float* W1  = (const float*)d_in[14];
    const float* b1  = (const float*)d_in[15];
    const float* W2  = (const float*)d_in[16];
    const float* b2  = (const float*)d_in[17];
    float* out = (float*)d_out;

    // workspace layout (~37 MB)
    unsigned short* hbh = (unsigned short*)d_ws;            // [ROWS][256]
    unsigned short* hbl = hbh + (size_t)ROWS * HIDN;
    unsigned short* h2h = hbl + (size_t)ROWS * HIDN;        // fused-layer output
    unsigned short* h2l = h2h + (size_t)ROWS * HIDN;
    float*          ir  = (float*)(h2l + (size_t)ROWS * HIDN);
    float*          fr  = ir + (size_t)ROWS * NH;
    unsigned short* WpTh = (unsigned short*)(fr + (size_t)ROWS * NH);
    unsigned short* WpTl = WpTh + (size_t)HIDN * KPAD;
    unsigned short* Wth  = WpTl + (size_t)HIDN * KPAD;
    unsigned short* Wtl  = Wth + (size_t)2 * 1024 * 256;
    // pack_x outputs alias h2h/h2l (dead until first fused layer writes them)
    unsigned short* xh = h2h;
    unsigned short* xl = h2l;

    pack_x<<<(ROWS * KPAD + 255) / 256, 256, 0, stream>>>(x, xh, xl);
    pack_w2<<<140, 256, 0, stream>>>(Wp, Wq, Wk, Wv, Wo, WpTh, WpTl, Wth, Wtl);

    // input projection: hb = x @ Wp + bp (split)
    gemm_mfma3<<<dim3(128, 2), 256, 0, stream>>>(
        xh, xl, WpTh, WpTl, bp, hbh, hbl, ROWS, HIDN, KPAD);

    // layer-0 gates
    ifproj<<<ROWS / 4, 256, 0, stream>>>(hbh, hbl, wi, wf, bi, bf, ir, fr);

    // layer 0
    fused_layer<<<BATCH * NH, 512, 81920, stream>>>(
        hbh, hbl, Wth, Wtl, bo, ir, fr, h2h, h2l);
    // LN + layer-1 gates
    layernorm_gate<<<ROWS / 4, 256, 0, stream>>>(
        h2h, h2l, hbh, hbl, lng, lnb,
        wi + (size_t)HIDN * NH, wf + (size_t)HIDN * NH, bi + NH, bf + NH, ir, fr);

    // layer 1
    fused_layer<<<BATCH * NH, 512, 81920, stream>>>(
        hbh, hbl, Wth + (size_t)1024 * 256, Wtl + (size_t)1024 * 256,
        bo + HIDN, ir, fr, h2h, h2l);

    // final LN fused into the head (only t = T-1 is consumed)
    head_ln_mlp<<<BATCH, 128, 0, stream>>>(
        h2h, h2l, lng + HIDN, lnb + HIDN, W1, b1, W2, b2, out);
}